// Round 4
// baseline (1923.552 us; speedup 1.0000x reference)
//
#include <hip/hip_runtime.h>
#include <math.h>

// Problem constants
#define B_    32
#define NR_   4096
#define DIN_  384
#define DCTX_ 128
#define H__   64
#define A__   16
#define NROW_ (B_ * NR_)   // 131072

// workspace layout (bytes)
#define WS_SUMS  0         // double[2]
#define WS_BAR   64        // int[16*3*32]
#define WS_SELW  6208      // int[512]
#define WS_SSC   8256      // float[512]
#define WS_SC0   10304     // float[512]
#define WS_ESUM  12352     // double[32*16*8]
#define WS_NSUM  45120     // double[32*16*8]
#define WS_CUR   77888     // float[512*64]  (owner-published cur, per bs)
#define WS_CUR0  208960    // float[512*64]  (slice-0 fallback cur, per bs)
#define WS_EMBT  340480    // float[64*131072] (k-major)
#define WS_ZERO  12352     // memset range [0, WS_ZERO): sums + bar + selw

__device__ __forceinline__ float frelu(float x) { return fmaxf(x, 0.0f); }

// ---------------------------------------------------------------------------
// K1: fused VAE. grid = (B*NR)/64 = 2048 blocks, 256 threads.
// 64-row tile, thread grid 16x16, each thread a 4x4 register tile.
// v4: waves_per_eu(3) floor (VGPR cap 170 -> no scratch spills; round-3's
//     launch_bounds(256,4) forced VGPR=64 + ~480 MB spill traffic);
//     phase-2a unroll 4->2 to keep peak live regs ~<=128.
// ---------------------------------------------------------------------------
struct alignas(16) Smem {
  union {
    struct { float As[32][68]; float Bs[32][68]; } p1;  // phase-1 staging
    float zT[64][68];                                   // z transposed
    double red[256];                                    // phase-4 reduction
  } u;
  float hT[64][68];     // h transposed; reused as tT in phase 3
  float rsq[16][66];    // per-row z^2 partials
  float nrm[64];        // row norms of z
};

__global__ __launch_bounds__(256) __attribute__((amdgpu_waves_per_eu(3)))
void vae_kernel(const float* __restrict__ roles,
                const float* __restrict__ eps,
                const float* __restrict__ W1,  const float* __restrict__ b1,
                const float* __restrict__ W21, const float* __restrict__ b21,
                const float* __restrict__ W22, const float* __restrict__ b22,
                const float* __restrict__ W3,  const float* __restrict__ b3,
                const float* __restrict__ W4,  const float* __restrict__ b4,
                float* __restrict__ embT, double* __restrict__ sums) {
  __shared__ Smem s;
  const int tid = threadIdx.x;
  const int tx = tid & 15, ty = tid >> 4;
  const int r0 = ty * 4, c0 = tx * 4;
  const long row_base = (long)blockIdx.x * 64;

  // ---------------- Phase 1: h = relu(roles @ W1 + b1), K = 384 ----------------
  float acc[4][4];
#pragma unroll
  for (int i = 0; i < 4; i++)
#pragma unroll
    for (int j = 0; j < 4; j++) acc[i][j] = 0.0f;

  const int lr  = tid >> 2;          // 0..63  (roles row within tile)
  const int lk0 = (tid & 3) * 8;     // 0,8,16,24 (k offset)
  const int bk  = tid >> 3;          // 0..31  (W1 row within chunk)
  const int bc0 = (tid & 7) * 8;     // 0..56  (W1 col)

  for (int ko = 0; ko < DIN_; ko += 32) {
    float4 a0 = *(const float4*)&roles[(row_base + lr) * DIN_ + ko + lk0];
    float4 a1 = *(const float4*)&roles[(row_base + lr) * DIN_ + ko + lk0 + 4];
    float4 w0 = *(const float4*)&W1[(ko + bk) * H__ + bc0];
    float4 w1 = *(const float4*)&W1[(ko + bk) * H__ + bc0 + 4];
    s.u.p1.As[lk0 + 0][lr] = a0.x; s.u.p1.As[lk0 + 1][lr] = a0.y;
    s.u.p1.As[lk0 + 2][lr] = a0.z; s.u.p1.As[lk0 + 3][lr] = a0.w;
    s.u.p1.As[lk0 + 4][lr] = a1.x; s.u.p1.As[lk0 + 5][lr] = a1.y;
    s.u.p1.As[lk0 + 6][lr] = a1.z; s.u.p1.As[lk0 + 7][lr] = a1.w;
    *(float4*)&s.u.p1.Bs[bk][bc0]     = w0;
    *(float4*)&s.u.p1.Bs[bk][bc0 + 4] = w1;
    __syncthreads();
#pragma unroll
    for (int kk = 0; kk < 32; kk++) {
      float4 av = *(const float4*)&s.u.p1.As[kk][r0];
      float4 bv = *(const float4*)&s.u.p1.Bs[kk][c0];
      float a_[4] = {av.x, av.y, av.z, av.w};
      float b_[4] = {bv.x, bv.y, bv.z, bv.w};
#pragma unroll
      for (int i = 0; i < 4; i++)
#pragma unroll
        for (int j = 0; j < 4; j++) acc[i][j] = fmaf(a_[i], b_[j], acc[i][j]);
    }
    __syncthreads();
  }
  // bias + relu -> hT[k][r]
  {
    float4 bj = *(const float4*)&b1[c0];
    float bb[4] = {bj.x, bj.y, bj.z, bj.w};
#pragma unroll
    for (int j = 0; j < 4; j++)
#pragma unroll
      for (int i = 0; i < 4; i++)
        s.hT[c0 + j][r0 + i] = frelu(acc[i][j] + bb[j]);
  }
  __syncthreads();

  // ---------------- Phase 2a: mu, log_var, z, kld ----------------
  float mu[4][4], lv[4][4];
#pragma unroll
  for (int i = 0; i < 4; i++)
#pragma unroll
    for (int j = 0; j < 4; j++) { mu[i][j] = 0.0f; lv[i][j] = 0.0f; }
#pragma unroll 2
  for (int k = 0; k < 64; k++) {
    float4 hv  = *(const float4*)&s.hT[k][r0];
    float4 w21 = *(const float4*)&W21[k * H__ + c0];
    float4 w22 = *(const float4*)&W22[k * H__ + c0];
    float h_[4] = {hv.x, hv.y, hv.z, hv.w};
    float a_[4] = {w21.x, w21.y, w21.z, w21.w};
    float b_[4] = {w22.x, w22.y, w22.z, w22.w};
#pragma unroll
    for (int i = 0; i < 4; i++)
#pragma unroll
      for (int j = 0; j < 4; j++) {
        mu[i][j] = fmaf(h_[i], a_[j], mu[i][j]);
        lv[i][j] = fmaf(h_[i], b_[j], lv[i][j]);
      }
  }
  const float VAR2C = (float)0.010000000000000002;   // STD2*STD2 as in ref
  const float C1    = (float)5.605170185988091;      // 1.0 - log(VAR2)
  double kacc = 0.0;
  float z[4][4];
  {
    float4 b21v = *(const float4*)&b21[c0];
    float4 b22v = *(const float4*)&b22[c0];
    float bb21[4] = {b21v.x, b21v.y, b21v.z, b21v.w};
    float bb22[4] = {b22v.x, b22v.y, b22v.z, b22v.w};
#pragma unroll
    for (int i = 0; i < 4; i++) {
      float4 ev = *(const float4*)&eps[(row_base + r0 + i) * H__ + c0];
      float e_[4] = {ev.x, ev.y, ev.z, ev.w};
#pragma unroll
      for (int j = 0; j < 4; j++) {
        float muv = mu[i][j] + bb21[j];
        float lvv = lv[i][j] + bb22[j];
        float zz  = muv + e_[j] * (expf(0.5f * lvv) * 0.1f);
        z[i][j] = zz;
        kacc += (double)((C1 + lvv) - (muv * muv + expf(lvv)) / VAR2C);
      }
    }
  }
  // row sums of z^2 and zT
#pragma unroll
  for (int i = 0; i < 4; i++) {
    float sq = 0.0f;
#pragma unroll
    for (int j = 0; j < 4; j++) {
      sq = fmaf(z[i][j], z[i][j], sq);
      s.u.zT[c0 + j][r0 + i] = z[i][j];
    }
    s.rsq[tx][r0 + i] = sq;
  }
  __syncthreads();
  if (tid < 64) {
    float t = 0.0f;
    for (int x = 0; x < 16; x++) t += s.rsq[x][tid];
    s.nrm[tid] = fmaxf(sqrtf(t), 1e-12f);
  }
  __syncthreads();

  // ---------------- embT epilogue: embT[k][global_row] = z/||z|| ----------------
  {
    const int k  = tid >> 2;           // 0..63
    const int rs = (tid & 3) * 16;     // 0,16,32,48
#pragma unroll
    for (int q = 0; q < 4; q++) {
      float4 zv = *(const float4*)&s.u.zT[k][rs + 4 * q];
      float4 ov;
      ov.x = zv.x / s.nrm[rs + 4 * q + 0];
      ov.y = zv.y / s.nrm[rs + 4 * q + 1];
      ov.z = zv.z / s.nrm[rs + 4 * q + 2];
      ov.w = zv.w / s.nrm[rs + 4 * q + 3];
      *(float4*)&embT[(size_t)k * NROW_ + row_base + rs + 4 * q] = ov;
    }
  }

  // ---------------- Phase 2b: t = relu(z @ W3 + b3) -> tT (reuse hT) ----------------
  float ta[4][4];
#pragma unroll
  for (int i = 0; i < 4; i++)
#pragma unroll
    for (int j = 0; j < 4; j++) ta[i][j] = 0.0f;
#pragma unroll 4
  for (int k = 0; k < 64; k++) {
    float4 zv = *(const float4*)&s.u.zT[k][r0];
    float4 wv = *(const float4*)&W3[k * H__ + c0];
    float z_[4] = {zv.x, zv.y, zv.z, zv.w};
    float w_[4] = {wv.x, wv.y, wv.z, wv.w};
#pragma unroll
    for (int i = 0; i < 4; i++)
#pragma unroll
      for (int j = 0; j < 4; j++) ta[i][j] = fmaf(z_[i], w_[j], ta[i][j]);
  }
  __syncthreads();   // everyone done reading hT/zT before overwrite
  {
    float4 b3v = *(const float4*)&b3[c0];
    float bb[4] = {b3v.x, b3v.y, b3v.z, b3v.w};
#pragma unroll
    for (int j = 0; j < 4; j++)
#pragma unroll
      for (int i = 0; i < 4; i++)
        s.hT[c0 + j][r0 + i] = frelu(ta[i][j] + bb[j]);
  }
  __syncthreads();

  // ---------------- Phase 3: x_hat = t @ W4 + b4, mse accumulation ----------------
  double macc = 0.0;
  for (int dc = 0; dc < DIN_; dc += 64) {
    float xa[4][4];
#pragma unroll
    for (int i = 0; i < 4; i++)
#pragma unroll
      for (int j = 0; j < 4; j++) xa[i][j] = 0.0f;
#pragma unroll 4
    for (int k = 0; k < 64; k++) {
      float4 tv = *(const float4*)&s.hT[k][r0];
      float4 wv = *(const float4*)&W4[k * DIN_ + dc + c0];
      float t_[4] = {tv.x, tv.y, tv.z, tv.w};
      float w_[4] = {wv.x, wv.y, wv.z, wv.w};
#pragma unroll
      for (int i = 0; i < 4; i++)
#pragma unroll
        for (int j = 0; j < 4; j++) xa[i][j] = fmaf(t_[i], w_[j], xa[i][j]);
    }
    float4 b4v = *(const float4*)&b4[dc + c0];
    float bb[4] = {b4v.x, b4v.y, b4v.z, b4v.w};
#pragma unroll
    for (int i = 0; i < 4; i++) {
      float4 rv = *(const float4*)&roles[(row_base + r0 + i) * DIN_ + dc + c0];
      float r_[4] = {rv.x, rv.y, rv.z, rv.w};
#pragma unroll
      for (int j = 0; j < 4; j++) {
        float d = (xa[i][j] + bb[j]) - r_[j];
        macc += (double)(d * d);
      }
    }
  }

  // ---------------- Phase 4: block reduce + atomics (red overlaps union) ----------
  __syncthreads();
  s.u.red[tid] = macc;
  __syncthreads();
  for (int st = 128; st > 0; st >>= 1) {
    if (tid < st) s.u.red[tid] += s.u.red[tid + st];
    __syncthreads();
  }
  if (tid == 0) atomicAdd(&sums[0], s.u.red[0]);
  __syncthreads();
  s.u.red[tid] = kacc;
  __syncthreads();
  for (int st = 128; st > 0; st >>= 1) {
    if (tid < st) s.u.red[tid] += s.u.red[tid + st];
    __syncthreads();
  }
  if (tid == 0) atomicAdd(&sums[1], s.u.red[0]);
}

// ---------------------------------------------------------------------------
// K2: finalize vae_loss
// ---------------------------------------------------------------------------
__global__ void finalize_kernel(const double* __restrict__ sums,
                                float* __restrict__ out) {
  double mse_total = sums[0] / ((double)NR_ * (double)DIN_);  // = sum_b mse_b
  double kld_total = -0.5 * (sums[1] / ((double)NR_ * (double)H__));
  out[512 + 32 + 2048] = (float)((mse_total + kld_total) / (double)B_);
}

// ---------------------------------------------------------------------------
// K3: selection scan v4. 256 blocks (8 slices x 32 batches), 256 threads.
// Bit-identical to v3 semantics; changes are latency-structural only:
//   - ctx-portion of the Wc matvec precomputed as fmaf-chain PREFIX (exact
//     same association); hist-rows of Wc preloaded into registers.
//   - owner block publishes cur (from LDS) + score to per-step L2 buffers;
//     consumers do one coalesced read instead of 64 HBM-strided gathers x8.
//   - cross-block reads use agent-scope relaxed atomic loads (L1-bypass).
// ---------------------------------------------------------------------------
__device__ __forceinline__ void batch_barrier(int* c) {
  __threadfence();   // make this block's prior global stores agent-visible
  __syncthreads();
  if (threadIdx.x == 0) {
    __hip_atomic_fetch_add(c, 1, __ATOMIC_ACQ_REL, __HIP_MEMORY_SCOPE_AGENT);
    while (__hip_atomic_load(c, __ATOMIC_ACQUIRE, __HIP_MEMORY_SCOPE_AGENT) < 8) {}
  }
  __syncthreads();
}

template <typename T>
__device__ __forceinline__ T aload(const T* p) {
  return __hip_atomic_load(p, __ATOMIC_RELAXED, __HIP_MEMORY_SCOPE_AGENT);
}

__global__ __launch_bounds__(256)
void select_kernel(const float* __restrict__ embT,
                   const float* __restrict__ contexts,
                   const float* __restrict__ rand_vals,
                   const float* __restrict__ Wc, const float* __restrict__ bc,
                   const float* __restrict__ init_emb,
                   char* __restrict__ ws,
                   float* __restrict__ out) {
  __shared__ float sEmb[64 * 512];   // k-major slice [k][row], 128 KB
  __shared__ float sexp[512];
  __shared__ float hist[64], cur[64], cvec[64], ctxs[128];
  __shared__ float cpart[4][64];
  __shared__ float cconst[4][64];
  __shared__ double wtot[4];
  __shared__ int seli;

  int*    bar    = (int*)(ws + WS_BAR);
  int*    selw   = (int*)(ws + WS_SELW);
  float*  sscore = (float*)(ws + WS_SSC);
  float*  sc0    = (float*)(ws + WS_SC0);
  double* esum   = (double*)(ws + WS_ESUM);
  double* nsum   = (double*)(ws + WS_NSUM);
  float*  curb   = (float*)(ws + WS_CUR);
  float*  cur0b  = (float*)(ws + WS_CUR0);

  const int tid   = threadIdx.x;
  const int slice = blockIdx.x >> 5;   // 0..7
  const int batch = blockIdx.x & 31;   // 0..31 (slices of a batch share XCD)
  const int lane  = tid & 63, wid = tid >> 6;
  const int h = lane, q = wid;
  const size_t rowB  = (size_t)batch * NR_;
  const size_t base0 = rowB + (size_t)slice * 512;
  float lp = 0.0f;

  // one-time slice load: sEmb[k][j] = embT[k][base0 + j]
  for (int i = tid; i < 64 * 128; i += 256) {
    const int k = i >> 7, j4 = (i & 127) << 2;
    *(float4*)&sEmb[k * 512 + j4] =
        *(const float4*)&embT[(size_t)k * NROW_ + base0 + j4];
  }
  if (tid < 64) { hist[tid] = init_emb[tid]; cur[tid] = init_emb[tid]; }
  if (tid < 128) ctxs[tid] = contexts[batch * DCTX_ + tid];
  __syncthreads();

  // preload Wc hist-rows into regs (q2: rows 128..143, q3: rows 144..191)
  float wch[48];
  if (q == 2) {
#pragma unroll
    for (int j = 0; j < 16; j++) wch[j] = Wc[(128 + j) * H__ + h];
  } else if (q == 3) {
#pragma unroll
    for (int j = 0; j < 48; j++) wch[j] = Wc[(144 + j) * H__ + h];
  }
  // ctx-only fmaf-chain prefixes (same association as v3's per-step loop)
  {
    float part = 0.0f;
    const int k0 = 48 * q;
    const int k1 = (k0 + 48 < 128) ? (k0 + 48) : 128;
    for (int k = k0; k < k1; k++) part = fmaf(ctxs[k], Wc[k * H__ + h], part);
    cconst[q][h] = part;   // q3: 0
  }
  __syncthreads();

  for (int step = 0; step < A__; step++) {
    const float  r  = rand_vals[batch * A__ + step];
    const double rd = (double)r;
    const int    bs = batch * A__ + step;

    // layernorm(hist + cur) on wave 0
    if (tid < 64) {
      float v = hist[tid] + cur[tid];
      float sum = v;
      for (int o = 32; o > 0; o >>= 1) sum += __shfl_xor(sum, o);
      float m = sum / 64.0f;
      float d = v - m;
      float s2 = d * d;
      for (int o = 32; o > 0; o >>= 1) s2 += __shfl_xor(s2, o);
      hist[tid] = d / sqrtf(s2 / 64.0f + 1e-5f);
    }
    __syncthreads();
    // continue the fmaf chains with hist terms (exact v3 association)
    {
      float part = cconst[q][h];
      if (q == 2) {
#pragma unroll
        for (int j = 0; j < 16; j++) part = fmaf(hist[j], wch[j], part);
      } else if (q == 3) {
#pragma unroll
        for (int j = 0; j < 48; j++) part = fmaf(hist[16 + j], wch[j], part);
      }
      cpart[q][h] = part;
    }
    __syncthreads();
    if (tid < 64) {
      float a = bc[tid] + cpart[0][tid] + cpart[1][tid] + cpart[2][tid] + cpart[3][tid];
      float qq = a * a;
      for (int o = 32; o > 0; o >>= 1) qq += __shfl_xor(qq, o);
      cvec[tid] = a / fmaxf(sqrtf(qq), 1e-12f);
      if (tid == 0) seli = 0x7fffffff;
    }
    __syncthreads();
    // dots for local rows 2*tid, 2*tid+1 (LDS only; shift 1.0 valid: |dot|<=1)
    float d0 = 0.0f, d1 = 0.0f;
    const float2* e2 = (const float2*)sEmb;
#pragma unroll 8
    for (int k = 0; k < 64; k++) {
      float2 ev = e2[k * 256 + tid];
      float c = cvec[k];
      d0 = fmaf(ev.x, c, d0);
      d1 = fmaf(ev.y, c, d1);
    }
    float e0 = expf(d0 - 1.0f), e1 = expf(d1 - 1.0f);
    double p = (double)e0 + (double)e1;
    double t = p;
    for (int o = 32; o > 0; o >>= 1) t += __shfl_xor(t, o);
    if (lane == 0) wtot[wid] = t;
    __syncthreads();
    if (tid == 0)
      esum[bs * 8 + slice] = ((wtot[0] + wtot[1]) + wtot[2]) + wtot[3];
    batch_barrier(&bar[(step * 3 + 0) * 32 + batch]);

    // f64 denom over 8 slices (ascending); f32-normalize (matches ref rounding)
    double denom = 0.0;
#pragma unroll
    for (int sx = 0; sx < 8; sx++) denom += aload(&esum[bs * 8 + sx]);
    float s0 = (float)((double)e0 / denom);
    float s1 = (float)((double)e1 / denom);
    ((float2*)sexp)[tid] = make_float2(s0, s1);
    double p2 = (double)s0 + (double)s1;
    double ip = p2;
    for (int o = 1; o < 64; o <<= 1) {
      double u = __shfl_up(ip, o);
      if (lane >= o) ip += u;
    }
    __syncthreads();
    if (lane == 63) wtot[wid] = ip;
    __syncthreads();
    if (tid == 0)
      nsum[bs * 8 + slice] = ((wtot[0] + wtot[1]) + wtot[2]) + wtot[3];
    batch_barrier(&bar[(step * 3 + 1) * 32 + batch]);

    // bases from nsums: identical f64 association as local scan -> no cracks
    double base = 0.0;
    for (int sx = 0; sx < slice; sx++) base += aload(&nsum[bs * 8 + sx]);
    double wbase = 0.0;
    for (int w = 0; w < wid; w++) wbase += wtot[w];
    double c = base + wbase + (ip - p2);   // exclusive prefix before row 2*tid
    int cand = 0x7fffffff;
    double cc = c + (double)s0;
    if (cc > rd) cand = 2 * tid;
    else { cc += (double)s1; if (cc > rd) cand = 2 * tid + 1; }
    if (cand != 0x7fffffff && rd >= base) atomicMin(&seli, cand);
    __syncthreads();
    const bool is_owner = (seli != 0x7fffffff) && (rd >= base);
    if (is_owner) {
      if (tid == 0) {
        selw[bs]   = slice * 512 + seli + 1;   // +1: 0 means "unset"
        sscore[bs] = sexp[seli];
      }
      if (tid < 64) curb[bs * 64 + tid] = sEmb[tid * 512 + seli];
    }
    if (slice == 0) {
      if (tid == 0) sc0[bs] = sexp[0];                      // fallback score
      if (tid < 64) cur0b[bs * 64 + tid] = sEmb[tid * 512]; // fallback cur
    }
    batch_barrier(&bar[(step * 3 + 2) * 32 + batch]);

    const int sv  = aload(&selw[bs]);
    const int sel = sv ? sv - 1 : 0;
    if (slice == 0 && tid == 0) {
      float sc = sv ? aload(&sscore[bs]) : aload(&sc0[bs]);
      lp += logf(sc);
      out[batch * A__ + step] = (float)sel;
    }
    if (tid < 64)
      cur[tid] = sv ? aload(&curb[bs * 64 + tid]) : aload(&cur0b[bs * 64 + tid]);
    __syncthreads();
  }
  if (slice == 0 && tid == 0) out[512 + batch] = lp;
  if (slice == 0 && tid < 64) out[512 + 32 + batch * H__ + tid] = hist[tid];
}

// ---------------------------------------------------------------------------
extern "C" void kernel_launch(void* const* d_in, const int* in_sizes, int n_in,
                              void* d_out, int out_size, void* d_ws, size_t ws_size,
                              hipStream_t stream) {
  (void)in_sizes; (void)n_in; (void)out_size; (void)ws_size;
  const float* roles    = (const float*)d_in[0];
  const float* contexts = (const float*)d_in[1];
  const float* eps      = (const float*)d_in[2];
  const float* rand_v   = (const float*)d_in[3];
  // d_in[4] = agent_num (unused; A=16 hardcoded)
  const float* W1  = (const float*)d_in[5];
  const float* b1  = (const float*)d_in[6];
  const float* W21 = (const float*)d_in[7];
  const float* b21 = (const float*)d_in[8];
  const float* W22 = (const float*)d_in[9];
  const float* b22 = (const float*)d_in[10];
  const float* W3  = (const float*)d_in[11];
  const float* b3  = (const float*)d_in[12];
  const float* W4  = (const float*)d_in[13];
  const float* b4  = (const float*)d_in[14];
  const float* Wc  = (const float*)d_in[15];
  const float* bc  = (const float*)d_in[16];
  const float* iem = (const float*)d_in[17];
  float* out = (float*)d_out;

  char*   ws   = (char*)d_ws;
  double* sums = (double*)(ws + WS_SUMS);
  float*  embT = (float*)(ws + WS_EMBT);    // [H][B*NR] floats, 32 MB

  hipMemsetAsync(d_ws, 0, WS_ZERO, stream);  // sums + barriers + sel slots
  vae_kernel<<<(B_ * NR_) / 64, 256, 0, stream>>>(
      roles, eps, W1, b1, W21, b21, W22, b22, W3, b3, W4, b4, embT, sums);
  finalize_kernel<<<1, 1, 0, stream>>>(sums, out);
  select_kernel<<<8 * B_, 256, 0, stream>>>(embT, contexts, rand_v, Wc, bc, iem,
                                            ws, out);
}

// Round 5
// 1067.867 us; speedup vs baseline: 1.8013x; 1.8013x over previous
//
#include <hip/hip_runtime.h>
#include <math.h>

// Problem constants
#define B_    32
#define NR_   4096
#define DIN_  384
#define DCTX_ 128
#define H__   64
#define A__   16
#define NROW_ (B_ * NR_)   // 131072

// workspace layout (bytes)
#define WS_SUMS  0         // double[2]
#define WS_BAR   64        // int[16*2*32]
#define WS_SELW  6208      // int[512]
#define WS_SSC   8256      // float[512]
#define WS_SC0   10304     // float[512]
#define WS_ESUM  12352     // double[32*16*8]
#define WS_CUR   77888     // float[512*64]  (owner-published cur, per bs)
#define WS_CUR0  208960    // float[512*64]  (slice-0 fallback cur, per bs)
#define WS_EMBT  340480    // float[64*131072] (k-major)
#define WS_ZERO  12352     // memset range [0, WS_ZERO): sums + bar + selw

__device__ __forceinline__ float frelu(float x) { return fmaxf(x, 0.0f); }

// ---------------------------------------------------------------------------
// K1: fused VAE — verbatim round-3 config (measured 535 us).
// grid = 2048 blocks x 256 threads; 64-row tile; 4x4 register tiles.
// launch_bounds(256,4): VGPR=64 (spills to scratch) but 44% occupancy —
// measured faster than the no-spill/low-occupancy variants (r4 post-mortem).
// ---------------------------------------------------------------------------
struct alignas(16) Smem {
  union {
    struct { float As[32][68]; float Bs[32][68]; } p1;  // phase-1 staging
    float zT[64][68];                                   // z transposed
    double red[256];                                    // phase-4 reduction
  } u;
  float hT[64][68];     // h transposed; reused as tT in phase 3
  float rsq[16][66];    // per-row z^2 partials
  float nrm[64];        // row norms of z
};

__global__ __launch_bounds__(256, 4)
void vae_kernel(const float* __restrict__ roles,
                const float* __restrict__ eps,
                const float* __restrict__ W1,  const float* __restrict__ b1,
                const float* __restrict__ W21, const float* __restrict__ b21,
                const float* __restrict__ W22, const float* __restrict__ b22,
                const float* __restrict__ W3,  const float* __restrict__ b3,
                const float* __restrict__ W4,  const float* __restrict__ b4,
                float* __restrict__ embT, double* __restrict__ sums) {
  __shared__ Smem s;
  const int tid = threadIdx.x;
  const int tx = tid & 15, ty = tid >> 4;
  const int r0 = ty * 4, c0 = tx * 4;
  const long row_base = (long)blockIdx.x * 64;

  // ---------------- Phase 1: h = relu(roles @ W1 + b1), K = 384 ----------------
  float acc[4][4];
#pragma unroll
  for (int i = 0; i < 4; i++)
#pragma unroll
    for (int j = 0; j < 4; j++) acc[i][j] = 0.0f;

  const int lr  = tid >> 2;          // 0..63  (roles row within tile)
  const int lk0 = (tid & 3) * 8;     // 0,8,16,24 (k offset)
  const int bk  = tid >> 3;          // 0..31  (W1 row within chunk)
  const int bc0 = (tid & 7) * 8;     // 0..56  (W1 col)

  for (int ko = 0; ko < DIN_; ko += 32) {
    float4 a0 = *(const float4*)&roles[(row_base + lr) * DIN_ + ko + lk0];
    float4 a1 = *(const float4*)&roles[(row_base + lr) * DIN_ + ko + lk0 + 4];
    float4 w0 = *(const float4*)&W1[(ko + bk) * H__ + bc0];
    float4 w1 = *(const float4*)&W1[(ko + bk) * H__ + bc0 + 4];
    s.u.p1.As[lk0 + 0][lr] = a0.x; s.u.p1.As[lk0 + 1][lr] = a0.y;
    s.u.p1.As[lk0 + 2][lr] = a0.z; s.u.p1.As[lk0 + 3][lr] = a0.w;
    s.u.p1.As[lk0 + 4][lr] = a1.x; s.u.p1.As[lk0 + 5][lr] = a1.y;
    s.u.p1.As[lk0 + 6][lr] = a1.z; s.u.p1.As[lk0 + 7][lr] = a1.w;
    *(float4*)&s.u.p1.Bs[bk][bc0]     = w0;
    *(float4*)&s.u.p1.Bs[bk][bc0 + 4] = w1;
    __syncthreads();
#pragma unroll
    for (int kk = 0; kk < 32; kk++) {
      float4 av = *(const float4*)&s.u.p1.As[kk][r0];
      float4 bv = *(const float4*)&s.u.p1.Bs[kk][c0];
      float a_[4] = {av.x, av.y, av.z, av.w};
      float b_[4] = {bv.x, bv.y, bv.z, bv.w};
#pragma unroll
      for (int i = 0; i < 4; i++)
#pragma unroll
        for (int j = 0; j < 4; j++) acc[i][j] = fmaf(a_[i], b_[j], acc[i][j]);
    }
    __syncthreads();
  }
  // bias + relu -> hT[k][r]
  {
    float4 bj = *(const float4*)&b1[c0];
    float bb[4] = {bj.x, bj.y, bj.z, bj.w};
#pragma unroll
    for (int j = 0; j < 4; j++)
#pragma unroll
      for (int i = 0; i < 4; i++)
        s.hT[c0 + j][r0 + i] = frelu(acc[i][j] + bb[j]);
  }
  __syncthreads();

  // ---------------- Phase 2a: mu, log_var, z, kld ----------------
  float mu[4][4], lv[4][4];
#pragma unroll
  for (int i = 0; i < 4; i++)
#pragma unroll
    for (int j = 0; j < 4; j++) { mu[i][j] = 0.0f; lv[i][j] = 0.0f; }
#pragma unroll 4
  for (int k = 0; k < 64; k++) {
    float4 hv  = *(const float4*)&s.hT[k][r0];
    float4 w21 = *(const float4*)&W21[k * H__ + c0];
    float4 w22 = *(const float4*)&W22[k * H__ + c0];
    float h_[4] = {hv.x, hv.y, hv.z, hv.w};
    float a_[4] = {w21.x, w21.y, w21.z, w21.w};
    float b_[4] = {w22.x, w22.y, w22.z, w22.w};
#pragma unroll
    for (int i = 0; i < 4; i++)
#pragma unroll
      for (int j = 0; j < 4; j++) {
        mu[i][j] = fmaf(h_[i], a_[j], mu[i][j]);
        lv[i][j] = fmaf(h_[i], b_[j], lv[i][j]);
      }
  }
  const float VAR2C = (float)0.010000000000000002;   // STD2*STD2 as in ref
  const float C1    = (float)5.605170185988091;      // 1.0 - log(VAR2)
  double kacc = 0.0;
  float z[4][4];
  {
    float4 b21v = *(const float4*)&b21[c0];
    float4 b22v = *(const float4*)&b22[c0];
    float bb21[4] = {b21v.x, b21v.y, b21v.z, b21v.w};
    float bb22[4] = {b22v.x, b22v.y, b22v.z, b22v.w};
#pragma unroll
    for (int i = 0; i < 4; i++) {
      float4 ev = *(const float4*)&eps[(row_base + r0 + i) * H__ + c0];
      float e_[4] = {ev.x, ev.y, ev.z, ev.w};
#pragma unroll
      for (int j = 0; j < 4; j++) {
        float muv = mu[i][j] + bb21[j];
        float lvv = lv[i][j] + bb22[j];
        float zz  = muv + e_[j] * (expf(0.5f * lvv) * 0.1f);
        z[i][j] = zz;
        kacc += (double)((C1 + lvv) - (muv * muv + expf(lvv)) / VAR2C);
      }
    }
  }
  // row sums of z^2 and zT
#pragma unroll
  for (int i = 0; i < 4; i++) {
    float sq = 0.0f;
#pragma unroll
    for (int j = 0; j < 4; j++) {
      sq = fmaf(z[i][j], z[i][j], sq);
      s.u.zT[c0 + j][r0 + i] = z[i][j];
    }
    s.rsq[tx][r0 + i] = sq;
  }
  __syncthreads();
  if (tid < 64) {
    float t = 0.0f;
    for (int x = 0; x < 16; x++) t += s.rsq[x][tid];
    s.nrm[tid] = fmaxf(sqrtf(t), 1e-12f);
  }
  __syncthreads();

  // ---------------- embT epilogue: embT[k][global_row] = z/||z|| ----------------
  {
    const int k  = tid >> 2;           // 0..63
    const int rs = (tid & 3) * 16;     // 0,16,32,48
#pragma unroll
    for (int q = 0; q < 4; q++) {
      float4 zv = *(const float4*)&s.u.zT[k][rs + 4 * q];
      float4 ov;
      ov.x = zv.x / s.nrm[rs + 4 * q + 0];
      ov.y = zv.y / s.nrm[rs + 4 * q + 1];
      ov.z = zv.z / s.nrm[rs + 4 * q + 2];
      ov.w = zv.w / s.nrm[rs + 4 * q + 3];
      *(float4*)&embT[(size_t)k * NROW_ + row_base + rs + 4 * q] = ov;
    }
  }

  // ---------------- Phase 2b: t = relu(z @ W3 + b3) -> tT (reuse hT) ----------------
  float ta[4][4];
#pragma unroll
  for (int i = 0; i < 4; i++)
#pragma unroll
    for (int j = 0; j < 4; j++) ta[i][j] = 0.0f;
#pragma unroll 4
  for (int k = 0; k < 64; k++) {
    float4 zv = *(const float4*)&s.u.zT[k][r0];
    float4 wv = *(const float4*)&W3[k * H__ + c0];
    float z_[4] = {zv.x, zv.y, zv.z, zv.w};
    float w_[4] = {wv.x, wv.y, wv.z, wv.w};
#pragma unroll
    for (int i = 0; i < 4; i++)
#pragma unroll
      for (int j = 0; j < 4; j++) ta[i][j] = fmaf(z_[i], w_[j], ta[i][j]);
  }
  __syncthreads();   // everyone done reading hT/zT before overwrite
  {
    float4 b3v = *(const float4*)&b3[c0];
    float bb[4] = {b3v.x, b3v.y, b3v.z, b3v.w};
#pragma unroll
    for (int j = 0; j < 4; j++)
#pragma unroll
      for (int i = 0; i < 4; i++)
        s.hT[c0 + j][r0 + i] = frelu(ta[i][j] + bb[j]);
  }
  __syncthreads();

  // ---------------- Phase 3: x_hat = t @ W4 + b4, mse accumulation ----------------
  double macc = 0.0;
  for (int dc = 0; dc < DIN_; dc += 64) {
    float xa[4][4];
#pragma unroll
    for (int i = 0; i < 4; i++)
#pragma unroll
      for (int j = 0; j < 4; j++) xa[i][j] = 0.0f;
#pragma unroll 4
    for (int k = 0; k < 64; k++) {
      float4 tv = *(const float4*)&s.hT[k][r0];
      float4 wv = *(const float4*)&W4[k * DIN_ + dc + c0];
      float t_[4] = {tv.x, tv.y, tv.z, tv.w};
      float w_[4] = {wv.x, wv.y, wv.z, wv.w};
#pragma unroll
      for (int i = 0; i < 4; i++)
#pragma unroll
        for (int j = 0; j < 4; j++) xa[i][j] = fmaf(t_[i], w_[j], xa[i][j]);
    }
    float4 b4v = *(const float4*)&b4[dc + c0];
    float bb[4] = {b4v.x, b4v.y, b4v.z, b4v.w};
#pragma unroll
    for (int i = 0; i < 4; i++) {
      float4 rv = *(const float4*)&roles[(row_base + r0 + i) * DIN_ + dc + c0];
      float r_[4] = {rv.x, rv.y, rv.z, rv.w};
#pragma unroll
      for (int j = 0; j < 4; j++) {
        float d = (xa[i][j] + bb[j]) - r_[j];
        macc += (double)(d * d);
      }
    }
  }

  // ---------------- Phase 4: block reduce + atomics (red overlaps union) ----------
  __syncthreads();
  s.u.red[tid] = macc;
  __syncthreads();
  for (int st = 128; st > 0; st >>= 1) {
    if (tid < st) s.u.red[tid] += s.u.red[tid + st];
    __syncthreads();
  }
  if (tid == 0) atomicAdd(&sums[0], s.u.red[0]);
  __syncthreads();
  s.u.red[tid] = kacc;
  __syncthreads();
  for (int st = 128; st > 0; st >>= 1) {
    if (tid < st) s.u.red[tid] += s.u.red[tid + st];
    __syncthreads();
  }
  if (tid == 0) atomicAdd(&sums[1], s.u.red[0]);
}

// ---------------------------------------------------------------------------
// K2: finalize vae_loss
// ---------------------------------------------------------------------------
__global__ void finalize_kernel(const double* __restrict__ sums,
                                float* __restrict__ out) {
  double mse_total = sums[0] / ((double)NR_ * (double)DIN_);  // = sum_b mse_b
  double kld_total = -0.5 * (sums[1] / ((double)NR_ * (double)H__));
  out[512 + 32 + 2048] = (float)((mse_total + kld_total) / (double)B_);
}

// ---------------------------------------------------------------------------
// K3: selection scan v5. 256 blocks (8 slices x 32 batches), 256 threads.
// v3 structure (plain stores, no fences, no per-thread uncached loads) with
// TWO barriers/step instead of three: slice bases derived from esum
// (base_s = (sum_{t<s} esum_t)/denom, same f64 association in every block ->
// unique owner; differs from v3's nsum bases by ~1e-9 absolute, far below
// measured selection margins ~1e-4). Owner publishes cur+score to
// step-indexed L2 slots (write-once addresses -> no stale-L1 hazard).
// ---------------------------------------------------------------------------
__device__ __forceinline__ void batch_barrier(int* c) {
  __syncthreads();   // s_waitcnt vmcnt(0) drains this block's stores to L2
  if (threadIdx.x == 0) {
    __hip_atomic_fetch_add(c, 1, __ATOMIC_ACQ_REL, __HIP_MEMORY_SCOPE_AGENT);
    while (__hip_atomic_load(c, __ATOMIC_ACQUIRE, __HIP_MEMORY_SCOPE_AGENT) < 8) {}
  }
  __syncthreads();
}

__global__ __launch_bounds__(256)
void select_kernel(const float* __restrict__ embT,
                   const float* __restrict__ contexts,
                   const float* __restrict__ rand_vals,
                   const float* __restrict__ Wc, const float* __restrict__ bc,
                   const float* __restrict__ init_emb,
                   char* __restrict__ ws,
                   float* __restrict__ out) {
  __shared__ float sEmb[64 * 512];   // k-major slice [k][row], 128 KB
  __shared__ float sexp[512];
  __shared__ float hist[64], cur[64], cvec[64], ctxs[128];
  __shared__ float cpart[4][64];
  __shared__ float cconst[4][64];
  __shared__ double wtot[4];
  __shared__ int seli;

  int*    bar    = (int*)(ws + WS_BAR);
  int*    selw   = (int*)(ws + WS_SELW);
  float*  sscore = (float*)(ws + WS_SSC);
  float*  sc0    = (float*)(ws + WS_SC0);
  double* esum   = (double*)(ws + WS_ESUM);
  float*  curb   = (float*)(ws + WS_CUR);
  float*  cur0b  = (float*)(ws + WS_CUR0);

  const int tid   = threadIdx.x;
  const int slice = blockIdx.x >> 5;   // 0..7
  const int batch = blockIdx.x & 31;   // 0..31 (slices of a batch share XCD)
  const int lane  = tid & 63, wid = tid >> 6;
  const int h = lane, q = wid;
  const size_t rowB  = (size_t)batch * NR_;
  const size_t base0 = rowB + (size_t)slice * 512;
  float lp = 0.0f;

  // one-time slice load: sEmb[k][j] = embT[k][base0 + j]
  for (int i = tid; i < 64 * 128; i += 256) {
    const int k = i >> 7, j4 = (i & 127) << 2;
    *(float4*)&sEmb[k * 512 + j4] =
        *(const float4*)&embT[(size_t)k * NROW_ + base0 + j4];
  }
  if (tid < 64) { hist[tid] = init_emb[tid]; cur[tid] = init_emb[tid]; }
  if (tid < 128) ctxs[tid] = contexts[batch * DCTX_ + tid];
  __syncthreads();

  // preload Wc hist-rows into regs (q2: rows 128..143, q3: rows 144..191)
  float wch[48];
  if (q == 2) {
#pragma unroll
    for (int j = 0; j < 16; j++) wch[j] = Wc[(128 + j) * H__ + h];
  } else if (q == 3) {
#pragma unroll
    for (int j = 0; j < 48; j++) wch[j] = Wc[(144 + j) * H__ + h];
  }
  // ctx-only fmaf-chain prefixes (same association as v3's per-step loop)
  {
    float part = 0.0f;
    const int k0 = 48 * q;
    const int k1 = (k0 + 48 < 128) ? (k0 + 48) : 128;
    for (int k = k0; k < k1; k++) part = fmaf(ctxs[k], Wc[k * H__ + h], part);
    cconst[q][h] = part;   // q3: 0
  }
  __syncthreads();

  for (int step = 0; step < A__; step++) {
    const float  r  = rand_vals[batch * A__ + step];
    const double rd = (double)r;
    const int    bs = batch * A__ + step;

    // layernorm(hist + cur) on wave 0
    if (tid < 64) {
      float v = hist[tid] + cur[tid];
      float sum = v;
      for (int o = 32; o > 0; o >>= 1) sum += __shfl_xor(sum, o);
      float m = sum / 64.0f;
      float d = v - m;
      float s2 = d * d;
      for (int o = 32; o > 0; o >>= 1) s2 += __shfl_xor(s2, o);
      hist[tid] = d / sqrtf(s2 / 64.0f + 1e-5f);
    }
    __syncthreads();
    // continue the fmaf chains with hist terms (exact v3 association)
    {
      float part = cconst[q][h];
      if (q == 2) {
#pragma unroll
        for (int j = 0; j < 16; j++) part = fmaf(hist[j], wch[j], part);
      } else if (q == 3) {
#pragma unroll
        for (int j = 0; j < 48; j++) part = fmaf(hist[16 + j], wch[j], part);
      }
      cpart[q][h] = part;
    }
    __syncthreads();
    if (tid < 64) {
      float a = bc[tid] + cpart[0][tid] + cpart[1][tid] + cpart[2][tid] + cpart[3][tid];
      float qq = a * a;
      for (int o = 32; o > 0; o >>= 1) qq += __shfl_xor(qq, o);
      cvec[tid] = a / fmaxf(sqrtf(qq), 1e-12f);
      if (tid == 0) seli = 0x7fffffff;
    }
    __syncthreads();
    // dots for local rows 2*tid, 2*tid+1 (LDS only; shift 1.0 valid: |dot|<=1)
    float d0 = 0.0f, d1 = 0.0f;
    const float2* e2 = (const float2*)sEmb;
#pragma unroll 8
    for (int k = 0; k < 64; k++) {
      float2 ev = e2[k * 256 + tid];
      float c = cvec[k];
      d0 = fmaf(ev.x, c, d0);
      d1 = fmaf(ev.y, c, d1);
    }
    float e0 = expf(d0 - 1.0f), e1 = expf(d1 - 1.0f);
    double p = (double)e0 + (double)e1;
    double t = p;
    for (int o = 32; o > 0; o >>= 1) t += __shfl_xor(t, o);
    if (lane == 0) wtot[wid] = t;
    __syncthreads();
    if (tid == 0)
      esum[bs * 8 + slice] = ((wtot[0] + wtot[1]) + wtot[2]) + wtot[3];
    batch_barrier(&bar[(step * 2 + 0) * 32 + batch]);

    // denom + slice base from esum (ascending order: identical f64 value in
    // every block -> consistent partition, unique owner)
    double pre = 0.0, denom = 0.0;
#pragma unroll
    for (int sx = 0; sx < 8; sx++) {
      if (sx == slice) pre = denom;
      denom += esum[bs * 8 + sx];
    }
    const double base = pre / denom;
    float s0 = (float)((double)e0 / denom);
    float s1 = (float)((double)e1 / denom);
    ((float2*)sexp)[tid] = make_float2(s0, s1);
    // local f64 exclusive scan (same association as v3)
    double p2 = (double)s0 + (double)s1;
    double ip = p2;
    for (int o = 1; o < 64; o <<= 1) {
      double u = __shfl_up(ip, o);
      if (lane >= o) ip += u;
    }
    __syncthreads();
    if (lane == 63) wtot[wid] = ip;
    __syncthreads();
    double wbase = 0.0;
#pragma unroll
    for (int w = 0; w < 4; w++) if (w < wid) wbase += wtot[w];
    double c = base + wbase + (ip - p2);   // exclusive prefix before row 2*tid
    int cand = 0x7fffffff;
    double cc = c + (double)s0;
    if (cc > rd) cand = 2 * tid;
    else { cc += (double)s1; if (cc > rd) cand = 2 * tid + 1; }
    if (cand != 0x7fffffff && rd >= base) atomicMin(&seli, cand);
    __syncthreads();
    const bool is_owner = (seli != 0x7fffffff) && (rd >= base);
    if (is_owner) {
      if (tid == 0) {
        selw[bs]   = slice * 512 + seli + 1;   // +1: 0 means "unset"
        sscore[bs] = sexp[seli];
      }
      if (tid < 64) curb[bs * 64 + tid] = sEmb[tid * 512 + seli];
    }
    if (slice == 0) {
      if (tid == 0) sc0[bs] = sexp[0];                      // fallback score
      if (tid < 64) cur0b[bs * 64 + tid] = sEmb[tid * 512]; // fallback cur
    }
    batch_barrier(&bar[(step * 2 + 1) * 32 + batch]);

    const int sv  = selw[bs];
    const int sel = sv ? sv - 1 : 0;
    if (slice == 0 && tid == 0) {
      float sc = sv ? sscore[bs] : sc0[bs];
      lp += logf(sc);
      out[batch * A__ + step] = (float)sel;
    }
    if (tid < 64)
      cur[tid] = sv ? curb[bs * 64 + tid] : cur0b[bs * 64 + tid];
    __syncthreads();
  }
  if (slice == 0 && tid == 0) out[512 + batch] = lp;
  if (slice == 0 && tid < 64) out[512 + 32 + batch * H__ + tid] = hist[tid];
}

// ---------------------------------------------------------------------------
extern "C" void kernel_launch(void* const* d_in, const int* in_sizes, int n_in,
                              void* d_out, int out_size, void* d_ws, size_t ws_size,
                              hipStream_t stream) {
  (void)in_sizes; (void)n_in; (void)out_size; (void)ws_size;
  const float* roles    = (const float*)d_in[0];
  const float* contexts = (const float*)d_in[1];
  const float* eps      = (const float*)d_in[2];
  const float* rand_v   = (const float*)d_in[3];
  // d_in[4] = agent_num (unused; A=16 hardcoded)
  const float* W1  = (const float*)d_in[5];
  const float* b1  = (const float*)d_in[6];
  const float* W21 = (const float*)d_in[7];
  const float* b21 = (const float*)d_in[8];
  const float* W22 = (const float*)d_in[9];
  const float* b22 = (const float*)d_in[10];
  const float* W3  = (const float*)d_in[11];
  const float* b3  = (const float*)d_in[12];
  const float* W4  = (const float*)d_in[13];
  const float* b4  = (const float*)d_in[14];
  const float* Wc  = (const float*)d_in[15];
  const float* bc  = (const float*)d_in[16];
  const float* iem = (const float*)d_in[17];
  float* out = (float*)d_out;

  char*   ws   = (char*)d_ws;
  double* sums = (double*)(ws + WS_SUMS);
  float*  embT = (float*)(ws + WS_EMBT);    // [H][B*NR] floats, 32 MB

  hipMemsetAsync(d_ws, 0, WS_ZERO, stream);  // sums + barriers + sel slots
  vae_kernel<<<(B_ * NR_) / 64, 256, 0, stream>>>(
      roles, eps, W1, b1, W21, b21, W22, b22, W3, b3, W4, b4, embT, sums);
  finalize_kernel<<<1, 1, 0, stream>>>(sums, out);
  select_kernel<<<8 * B_, 256, 0, stream>>>(embT, contexts, rand_v, Wc, bc, iem,
                                            ws, out);
}